// Round 5
// baseline (732.950 us; speedup 1.0000x reference)
//
#include <hip/hip_runtime.h>
#include <hip/hip_bf16.h>

// Problem constants (match reference)
#define NN 100000
#define NG 512
#define H  128

typedef _Float16 half8 __attribute__((ext_vector_type(8)));
typedef float f32x4 __attribute__((ext_vector_type(4)));

// ---------------------------------------------------------------------------
// Merged: blocks [0,128) transpose+fp16-convert W1/W2; blocks [128,..) dst hist
__global__ __launch_bounds__(256) void k_wprep_hist(const float* __restrict__ W1,
                                                    const float* __restrict__ W2,
                                                    _Float16* __restrict__ Wt1,
                                                    _Float16* __restrict__ Wt2,
                                                    const int* __restrict__ dst,
                                                    int* __restrict__ deg, int E) {
    int bb = blockIdx.x;
    if (bb < 128) {
        const float* W = (bb < 64) ? W1 : W2;
        _Float16* Wt = (bb < 64) ? Wt1 : Wt2;
        int i = (bb & 63) * 256 + threadIdx.x;    // 0..16383
        int k = i >> 7, n = i & 127;
        Wt[n * 128 + k] = (_Float16)W[i];
        return;
    }
    int e = (bb - 128) * 256 + threadIdx.x;
    if (e < E) atomicAdd(&deg[dst[e]], 1);
}

// per-block exclusive scan (256 elems), partial sums to bsum
__global__ __launch_bounds__(256) void k_scan_block(const int* __restrict__ deg,
                                                    int* __restrict__ rowptr,
                                                    int* __restrict__ bsum, int n) {
    __shared__ int s[256];
    int tid = threadIdx.x;
    int i = blockIdx.x * 256 + tid;
    int v = (i < n) ? deg[i] : 0;
    s[tid] = v;
    __syncthreads();
    #pragma unroll
    for (int off = 1; off < 256; off <<= 1) {
        int t = (tid >= off) ? s[tid - off] : 0;
        __syncthreads();
        s[tid] += t;
        __syncthreads();
    }
    if (i < n) rowptr[i] = s[tid] - v;            // exclusive within block
    if (tid == 255) bsum[blockIdx.x] = s[255];    // block total
}

// scan of block sums (nb <= 512), single block
__global__ __launch_bounds__(512) void k_scan_top(int* __restrict__ bsum, int nb) {
    __shared__ int s[512];
    int tid = threadIdx.x;
    int v = (tid < nb) ? bsum[tid] : 0;
    s[tid] = v;
    __syncthreads();
    #pragma unroll
    for (int off = 1; off < 512; off <<= 1) {
        int t = (tid >= off) ? s[tid - off] : 0;
        __syncthreads();
        s[tid] += t;
        __syncthreads();
    }
    if (tid < nb) bsum[tid] = s[tid] - v;         // exclusive
}

// finalize: rowptr += block offset; cursor = rowptr; dinv = rsqrt(deg+1)
__global__ __launch_bounds__(256) void k_scan_fin(int* __restrict__ rowptr,
                                                  const int* __restrict__ bsum,
                                                  const int* __restrict__ deg,
                                                  int* __restrict__ cursor,
                                                  float* __restrict__ dinv,
                                                  int n, int E) {
    int i = blockIdx.x * 256 + threadIdx.x;
    if (i >= n) return;
    int r = rowptr[i] + bsum[i >> 8];
    rowptr[i] = r;
    cursor[i] = r;
    dinv[i] = rsqrtf((float)deg[i] + 1.0f);       // +1 self-loop; always > 0
    if (i == 0) rowptr[n] = E;
}

// ---------------------------------------------------------------------------
// Fused: blocks [0,nfb) fill CSR col; blocks [nfb,..) do GEMM1
// (tS = (x@W1)*dinv[row], fp16 out). LDS-free MFMA GEMM.
__global__ __launch_bounds__(256) void k_fill_gemm1(
        const int* __restrict__ src, const int* __restrict__ dst,
        int* __restrict__ cursor, int* __restrict__ col, int E, int nfb,
        const float* __restrict__ x, const _Float16* __restrict__ Wt1,
        const float* __restrict__ dinv, _Float16* __restrict__ tS, int n) {
    if ((int)blockIdx.x < nfb) {
        int e = blockIdx.x * 256 + threadIdx.x;
        if (e >= E) return;
        int d = dst[e];
        int pos = atomicAdd(&cursor[d], 1);
        col[pos] = src[e];
        return;
    }
    const int row0 = ((int)blockIdx.x - nfb) * 64;
    const int tid = threadIdx.x;
    const int w = tid >> 6, lane = tid & 63;
    const int l16 = lane & 15, quad = lane >> 4;
    const int Arow = row0 + w * 16 + l16;
    f32x4 acc[8] = {};
    #pragma unroll
    for (int kk = 0; kk < 4; ++kk) {
        half8 af;
        if (Arow < n) {
            const float* ap = x + (size_t)Arow * H + kk * 32 + quad * 8;
            float4 a0 = ((const float4*)ap)[0];
            float4 a1 = ((const float4*)ap)[1];
            af[0] = (_Float16)a0.x; af[1] = (_Float16)a0.y;
            af[2] = (_Float16)a0.z; af[3] = (_Float16)a0.w;
            af[4] = (_Float16)a1.x; af[5] = (_Float16)a1.y;
            af[6] = (_Float16)a1.z; af[7] = (_Float16)a1.w;
        } else {
            #pragma unroll
            for (int j = 0; j < 8; ++j) af[j] = (_Float16)0.0f;
        }
        #pragma unroll
        for (int nt = 0; nt < 8; ++nt) {
            half8 bf = *((const half8*)(Wt1 + (nt * 16 + l16) * H + kk * 32 + quad * 8));
            acc[nt] = __builtin_amdgcn_mfma_f32_16x16x32_f16(af, bf, acc[nt], 0, 0, 0);
        }
    }
    #pragma unroll
    for (int r = 0; r < 4; ++r) {
        int R = row0 + w * 16 + quad * 4 + r;
        if (R < n) {
            float sc = dinv[R];
            _Float16* crow = tS + (size_t)R * H + l16;
            #pragma unroll
            for (int nt = 0; nt < 8; ++nt)
                crow[nt * 16] = (_Float16)(acc[nt][r] * sc);
        }
    }
}

// ---------------------------------------------------------------------------
// GEMM2, LDS-free: tS2 = (h1 @ W2) * dinv[row]
__global__ __launch_bounds__(256) void k_gemm2(const _Float16* __restrict__ h1,
                                               const _Float16* __restrict__ Wt2,
                                               const float* __restrict__ dinv,
                                               _Float16* __restrict__ tS2, int n) {
    const int row0 = blockIdx.x * 64;
    const int tid = threadIdx.x;
    const int w = tid >> 6, lane = tid & 63;
    const int l16 = lane & 15, quad = lane >> 4;
    const int Arow = row0 + w * 16 + l16;
    f32x4 acc[8] = {};
    #pragma unroll
    for (int kk = 0; kk < 4; ++kk) {
        half8 af;
        if (Arow < n) {
            af = ((const half8*)(h1 + (size_t)Arow * H))[kk * 4 + quad];
        } else {
            #pragma unroll
            for (int j = 0; j < 8; ++j) af[j] = (_Float16)0.0f;
        }
        #pragma unroll
        for (int nt = 0; nt < 8; ++nt) {
            half8 bf = *((const half8*)(Wt2 + (nt * 16 + l16) * H + kk * 32 + quad * 8));
            acc[nt] = __builtin_amdgcn_mfma_f32_16x16x32_f16(af, bf, acc[nt], 0, 0, 0);
        }
    }
    #pragma unroll
    for (int r = 0; r < 4; ++r) {
        int R = row0 + w * 16 + quad * 4 + r;
        if (R < n) {
            float sc = dinv[R];
            _Float16* crow = tS2 + (size_t)R * H + l16;
            #pragma unroll
            for (int nt = 0; nt < 8; ++nt)
                crow[nt * 16] = (_Float16)(acc[nt][r] * sc);
        }
    }
}

// ---------------------------------------------------------------------------
// 16B row-fragment load that BYPASSES L1 (agent-scope relaxed atomic ->
// global_load_dwordx2 sc0). Used ONLY in gather2 (no store stream there).
__device__ __forceinline__ half8 ld_row16_nol1(const _Float16* p) {
    union { unsigned long long u[2]; half8 h; } t;
    const unsigned long long* q = (const unsigned long long*)p;
    t.u[0] = __hip_atomic_load(q,     __ATOMIC_RELAXED, __HIP_MEMORY_SCOPE_AGENT);
    t.u[1] = __hip_atomic_load(q + 1, __ATOMIC_RELAXED, __HIP_MEMORY_SCOPE_AGENT);
    return t.h;
}

// ---------------------------------------------------------------------------
// 8-GROUP BURST gather core (r4 post-mortem: all prior nulls trace to the
// register allocator pinning outstanding row loads at 2 — VGPR_Count 28-36
// in every round. This core issues up to 8 group loads (32 rows) into 8
// NAMED half8 registers before any accumulate. The issue ladder is guarded
// by WAVE-UNIFORM `ng > G` branches (s_cbranch rungs), which structurally
// resists scheduler re-serialization, unlike r1's straight-line block.
// Callers use __launch_bounds__(256, 4) => VGPR cap 128 (16 waves/CU, the
// occupancy r4 showed is sufficient), so the ~70-VGPR live set fits.
// Validity: groups 0..ng-2 are always full; only the last group is lane-
// partial, handled by 0/1-weight fma. Out-of-range col slots clamp to
// `node` (always-valid row, weight 0). Poisson(16) => P(deg>32) ~ 1e-4;
// tail handled by a simple chunked loop.
template <bool NOL1>
__device__ __forceinline__ half8 ld_row(const _Float16* __restrict__ tS,
                                        int s, int l16) {
    if (NOL1) return ld_row16_nol1(tS + (size_t)s * H + l16 * 8);
    return ((const half8*)tS)[(size_t)s * 16 + l16];
}

template <bool NOL1>
__device__ __forceinline__ void gather_burst(const _Float16* __restrict__ tS,
                                             const int* __restrict__ col,
                                             int node, int e0, int e1,
                                             float acc[8]) {
    const int lane = threadIdx.x & 63;
    const int q = lane >> 4;
    const int l16 = lane & 15;
    const int m = e1 - e0;
    int cidx = (e0 + lane < e1) ? col[e0 + lane] : node;   // clamp -> safe row
    float a0[8] = {}, a1[8] = {};

    // self-loop row: all lanes load (broadcast lines), quarter 0 accumulates
    {
        half8 v = ((const half8*)tS)[(size_t)node * 16 + l16];
        float w = (q == 0) ? 1.0f : 0.0f;
        #pragma unroll
        for (int i = 0; i < 8; ++i) a0[i] = w * (float)v[i];
    }

    const int ng = (min(m, 32) + 3) >> 2;   // 0..8 burst groups
    half8 v0, v1, v2, v3, v4, v5, v6, v7;

    // ---- issue ladder: all loads before any accumulate ----
#define G_ISSUE(G, V) if (ng > G) { int s_ = __shfl(cidx, 4 * G + q); \
                                    V = ld_row<NOL1>(tS, s_, l16); }
    G_ISSUE(0, v0)
    G_ISSUE(1, v1)
    G_ISSUE(2, v2)
    G_ISSUE(3, v3)
    G_ISSUE(4, v4)
    G_ISSUE(5, v5)
    G_ISSUE(6, v6)
    G_ISSUE(7, v7)
#undef G_ISSUE

    // ---- accumulate (per-lane validity weight; only last group partial) ----
#define G_ACC(G, V, A) if (ng > G) { \
        float w_ = (4 * G + q < m) ? 1.0f : 0.0f; \
        _Pragma("unroll") \
        for (int i = 0; i < 8; ++i) A[i] += w_ * (float)V[i]; }
    G_ACC(0, v0, a0)
    G_ACC(1, v1, a1)
    G_ACC(2, v2, a0)
    G_ACC(3, v3, a1)
    G_ACC(4, v4, a0)
    G_ACC(5, v5, a1)
    G_ACC(6, v6, a0)
    G_ACC(7, v7, a1)
#undef G_ACC

    // ---- rare tail: deg > 32 (P ~ 1e-4) ----
    for (int base = e0 + 32; base < e1; base += 64) {
        int ce = base + lane;
        int cx = (ce < e1) ? col[ce] : node;
        int mm = min(64, e1 - base);
        int nf2 = (mm + 3) >> 2;
        for (int g = 0; g < nf2; ++g) {
            int s_ = __shfl(cx, 4 * g + q);
            half8 v = ld_row<NOL1>(tS, s_, l16);
            float w_ = (4 * g + q < mm) ? 1.0f : 0.0f;
            #pragma unroll
            for (int i = 0; i < 8; ++i) a0[i] += w_ * (float)v[i];
        }
    }

    #pragma unroll
    for (int i = 0; i < 8; ++i) {
        float t = a0[i] + a1[i];
        t += __shfl_xor(t, 16);
        t += __shfl_xor(t, 32);
        acc[i] = t;
    }
}

// gather layer 1: out (fp16) = relu(dinv[n]*(tS[n] + sum in-edges) + b)
__global__ __launch_bounds__(256, 4) void k_gather1(const _Float16* __restrict__ tS,
                                                    const int* __restrict__ rowptr,
                                                    const int* __restrict__ col,
                                                    const float* __restrict__ dinv,
                                                    const float* __restrict__ b,
                                                    _Float16* __restrict__ out, int n) {
    int node = blockIdx.x * 4 + (threadIdx.x >> 6);
    int lane = threadIdx.x & 63;
    int q = lane >> 4, l16 = lane & 15;
    if (node >= n) return;
    int e0 = rowptr[node], e1 = rowptr[node + 1];
    float acc[8];
    gather_burst<false>(tS, col, node, e0, e1, acc);
    if (q == 0) {
        float dn = dinv[node];
        const float4* b4 = (const float4*)b;
        float4 bb0 = b4[2 * l16], bb1 = b4[2 * l16 + 1];
        half8 hv;
        hv[0] = (_Float16)fmaxf(dn * acc[0] + bb0.x, 0.0f);
        hv[1] = (_Float16)fmaxf(dn * acc[1] + bb0.y, 0.0f);
        hv[2] = (_Float16)fmaxf(dn * acc[2] + bb0.z, 0.0f);
        hv[3] = (_Float16)fmaxf(dn * acc[3] + bb0.w, 0.0f);
        hv[4] = (_Float16)fmaxf(dn * acc[4] + bb1.x, 0.0f);
        hv[5] = (_Float16)fmaxf(dn * acc[5] + bb1.y, 0.0f);
        hv[6] = (_Float16)fmaxf(dn * acc[6] + bb1.z, 0.0f);
        hv[7] = (_Float16)fmaxf(dn * acc[7] + bb1.w, 0.0f);
        ((half8*)out)[(size_t)node * 16 + l16] = hv;
    }
}

// gather layer 2 fused with pool head: v = relu(...); pool[batch[n]] += dot(v, Wp)
__global__ __launch_bounds__(256, 4) void k_gather2(const _Float16* __restrict__ tS,
                                                    const int* __restrict__ rowptr,
                                                    const int* __restrict__ col,
                                                    const float* __restrict__ dinv,
                                                    const float* __restrict__ b,
                                                    const float* __restrict__ Wp,
                                                    const int* __restrict__ batch,
                                                    float* __restrict__ pool, int n) {
    int node = blockIdx.x * 4 + (threadIdx.x >> 6);
    int lane = threadIdx.x & 63;
    int l16 = lane & 15;
    if (node >= n) return;
    int e0 = rowptr[node], e1 = rowptr[node + 1];
    float acc[8];
    gather_burst<true>(tS, col, node, e0, e1, acc);
    float dn = dinv[node];
    const float4* b4 = (const float4*)b;
    const float4* w4 = (const float4*)Wp;
    float4 bb0 = b4[2 * l16], bb1 = b4[2 * l16 + 1];
    float4 wp0 = w4[2 * l16], wp1 = w4[2 * l16 + 1];
    float s = fmaxf(dn * acc[0] + bb0.x, 0.0f) * wp0.x +
              fmaxf(dn * acc[1] + bb0.y, 0.0f) * wp0.y +
              fmaxf(dn * acc[2] + bb0.z, 0.0f) * wp0.z +
              fmaxf(dn * acc[3] + bb0.w, 0.0f) * wp0.w +
              fmaxf(dn * acc[4] + bb1.x, 0.0f) * wp1.x +
              fmaxf(dn * acc[5] + bb1.y, 0.0f) * wp1.y +
              fmaxf(dn * acc[6] + bb1.z, 0.0f) * wp1.z +
              fmaxf(dn * acc[7] + bb1.w, 0.0f) * wp1.w;
    s += __shfl_xor(s, 1);
    s += __shfl_xor(s, 2);
    s += __shfl_xor(s, 4);
    s += __shfl_xor(s, 8);
    if (lane == 0) {
        int g = batch[node];
        atomicAdd(&pool[g], s);
    }
}

// ---------------------------------------------------------------------------
// batch is sorted: per-graph node counts via binary search (replaces 100K
// float atomics previously done in gather2).
__global__ __launch_bounds__(256) void final_out_kernel(const float* __restrict__ pool,
                                                        const int* __restrict__ batch,
                                                        const float* __restrict__ bp,
                                                        float* __restrict__ out, int g) {
    int i = blockIdx.x * 256 + threadIdx.x;
    if (i >= g) return;
    int lo = 0, hi = NN;
    while (lo < hi) { int mid = (lo + hi) >> 1; if (batch[mid] < i) lo = mid + 1; else hi = mid; }
    int s0 = lo;
    hi = NN;
    while (lo < hi) { int mid = (lo + hi) >> 1; if (batch[mid] < i + 1) lo = mid + 1; else hi = mid; }
    float c = (float)(lo - s0);
    out[i] = pool[i] / fmaxf(c, 1.0f) + bp[0];
}

// ---------------------------------------------------------------------------
extern "C" void kernel_launch(void* const* d_in, const int* in_sizes, int n_in,
                              void* d_out, int out_size, void* d_ws, size_t ws_size,
                              hipStream_t stream) {
    const float* x     = (const float*)d_in[0];
    const int*   ei    = (const int*)d_in[1];   // [2, E]: src = ei[0:E], dst = ei[E:2E]
    const int*   batch = (const int*)d_in[2];
    const float* W1    = (const float*)d_in[3];
    const float* b1    = (const float*)d_in[4];
    const float* W2    = (const float*)d_in[5];
    const float* b2    = (const float*)d_in[6];
    const float* Wp    = (const float*)d_in[7];
    const float* bp    = (const float*)d_in[8];
    float* out = (float*)d_out;

    const int E = in_sizes[1] / 2;   // 1,600,000
    const int* src = ei;
    const int* dst = ei + E;

    // workspace layout
    const size_t BUFH = (size_t)NN * H * sizeof(_Float16);   // 25.6 MB
    const size_t NI   = 401408;                               // >= (NN+1)*4, 4KB-mult
    char* ws = (char*)d_ws;
    size_t off = 0;
    _Float16* tS   = (_Float16*)(ws + off); off += BUFH;     // GEMM1 out (fp16)
    _Float16* h1   = (_Float16*)(ws + off); off += BUFH;     // layer-1 acts (fp16)
    _Float16* tS2  = (_Float16*)(ws + off); off += BUFH;     // GEMM2 out (fp16)
    int*      deg  = (int*)     (ws + off); off += NI;
    int*   rowptr  = (int*)     (ws + off); off += NI;
    int*   cursor  = (int*)     (ws + off); off += NI;
    float*    dinv = (float*)   (ws + off); off += NI;
    int*      col  = (int*)     (ws + off); off += ((size_t)E * 4 + 4095) / 4096 * 4096;
    _Float16* Wt1  = (_Float16*)(ws + off); off += 32768;
    _Float16* Wt2  = (_Float16*)(ws + off); off += 32768;
    int*      bsum = (int*)     (ws + off); off += 4096;
    float*    pool = (float*)   (ws + off); off += 2048;

    const int NB  = (NN + 255) / 256;   // 391 scan blocks
    const int NFB = (E + 255) / 256;    // 6250 fill/hist blocks
    const int NGB = (NN + 63) / 64;     // 1563 gemm blocks
    const int NGA = (NN + 3) / 4;       // 25000 gather blocks (4 nodes/block)

    // --- weights prep ∥ histogram (one dispatch), then scans ---
    hipMemsetAsync(deg, 0, NN * sizeof(int), stream);
    hipMemsetAsync(pool, 0, 2048, stream);
    k_wprep_hist<<<128 + NFB, 256, 0, stream>>>(W1, W2, Wt1, Wt2, dst, deg, E);
    k_scan_block<<<NB, 256, 0, stream>>>(deg, rowptr, bsum, NN);
    k_scan_top<<<1, 512, 0, stream>>>(bsum, NB);
    k_scan_fin<<<NB, 256, 0, stream>>>(rowptr, bsum, deg, cursor, dinv, NN, E);

    // --- fill CSR  ∥  GEMM1 (one dispatch, disjoint block ranges) ---
    k_fill_gemm1<<<NFB + NGB, 256, 0, stream>>>(src, dst, cursor, col, E, NFB,
                                                x, Wt1, dinv, tS, NN);

    // --- layer 1: burst gather then LDS-free MFMA GEMM2 ---
    k_gather1<<<NGA, 256, 0, stream>>>(tS, rowptr, col, dinv, b1, h1, NN);
    k_gemm2<<<NGB, 256, 0, stream>>>(h1, Wt2, dinv, tS2, NN);

    // --- layer 2 burst gather + pool head ---
    k_gather2<<<NGA, 256, 0, stream>>>(tS2, rowptr, col, dinv, b2, Wp,
                                       batch, pool, NN);

    // --- head ---
    final_out_kernel<<<(NG + 255) / 256, 256, 0, stream>>>(pool, batch, bp, out, NG);
}

// Round 6
// 699.834 us; speedup vs baseline: 1.0473x; 1.0473x over previous
//
#include <hip/hip_runtime.h>
#include <hip/hip_bf16.h>

// Problem constants (match reference)
#define NN 100000
#define NG 512
#define H  128

typedef _Float16 half8 __attribute__((ext_vector_type(8)));
typedef float f32x4 __attribute__((ext_vector_type(4)));

union h8f4 { f32x4 f; half8 h; };

// ---------------------------------------------------------------------------
// Merged: blocks [0,128) transpose+fp16-convert W1/W2; blocks [128,..) dst hist
__global__ __launch_bounds__(256) void k_wprep_hist(const float* __restrict__ W1,
                                                    const float* __restrict__ W2,
                                                    _Float16* __restrict__ Wt1,
                                                    _Float16* __restrict__ Wt2,
                                                    const int* __restrict__ dst,
                                                    int* __restrict__ deg, int E) {
    int bb = blockIdx.x;
    if (bb < 128) {
        const float* W = (bb < 64) ? W1 : W2;
        _Float16* Wt = (bb < 64) ? Wt1 : Wt2;
        int i = (bb & 63) * 256 + threadIdx.x;    // 0..16383
        int k = i >> 7, n = i & 127;
        Wt[n * 128 + k] = (_Float16)W[i];
        return;
    }
    int e = (bb - 128) * 256 + threadIdx.x;
    if (e < E) atomicAdd(&deg[dst[e]], 1);
}

// per-block exclusive scan (256 elems), partial sums to bsum
__global__ __launch_bounds__(256) void k_scan_block(const int* __restrict__ deg,
                                                    int* __restrict__ rowptr,
                                                    int* __restrict__ bsum, int n) {
    __shared__ int s[256];
    int tid = threadIdx.x;
    int i = blockIdx.x * 256 + tid;
    int v = (i < n) ? deg[i] : 0;
    s[tid] = v;
    __syncthreads();
    #pragma unroll
    for (int off = 1; off < 256; off <<= 1) {
        int t = (tid >= off) ? s[tid - off] : 0;
        __syncthreads();
        s[tid] += t;
        __syncthreads();
    }
    if (i < n) rowptr[i] = s[tid] - v;            // exclusive within block
    if (tid == 255) bsum[blockIdx.x] = s[255];    // block total
}

// scan of block sums (nb <= 512), single block
__global__ __launch_bounds__(512) void k_scan_top(int* __restrict__ bsum, int nb) {
    __shared__ int s[512];
    int tid = threadIdx.x;
    int v = (tid < nb) ? bsum[tid] : 0;
    s[tid] = v;
    __syncthreads();
    #pragma unroll
    for (int off = 1; off < 512; off <<= 1) {
        int t = (tid >= off) ? s[tid - off] : 0;
        __syncthreads();
        s[tid] += t;
        __syncthreads();
    }
    if (tid < nb) bsum[tid] = s[tid] - v;         // exclusive
}

// finalize: rowptr += block offset; cursor = rowptr; dinv = rsqrt(deg+1)
__global__ __launch_bounds__(256) void k_scan_fin(int* __restrict__ rowptr,
                                                  const int* __restrict__ bsum,
                                                  const int* __restrict__ deg,
                                                  int* __restrict__ cursor,
                                                  float* __restrict__ dinv,
                                                  int n, int E) {
    int i = blockIdx.x * 256 + threadIdx.x;
    if (i >= n) return;
    int r = rowptr[i] + bsum[i >> 8];
    rowptr[i] = r;
    cursor[i] = r;
    dinv[i] = rsqrtf((float)deg[i] + 1.0f);       // +1 self-loop; always > 0
    if (i == 0) rowptr[n] = E;
}

// ---------------------------------------------------------------------------
// Fused: blocks [0,nfb) fill CSR col; blocks [nfb,..) do GEMM1
// (tS = (x@W1)*dinv[row], fp16 out). LDS-free MFMA GEMM.
__global__ __launch_bounds__(256) void k_fill_gemm1(
        const int* __restrict__ src, const int* __restrict__ dst,
        int* __restrict__ cursor, int* __restrict__ col, int E, int nfb,
        const float* __restrict__ x, const _Float16* __restrict__ Wt1,
        const float* __restrict__ dinv, _Float16* __restrict__ tS, int n) {
    if ((int)blockIdx.x < nfb) {
        int e = blockIdx.x * 256 + threadIdx.x;
        if (e >= E) return;
        int d = dst[e];
        int pos = atomicAdd(&cursor[d], 1);
        col[pos] = src[e];
        return;
    }
    const int row0 = ((int)blockIdx.x - nfb) * 64;
    const int tid = threadIdx.x;
    const int w = tid >> 6, lane = tid & 63;
    const int l16 = lane & 15, quad = lane >> 4;
    const int Arow = row0 + w * 16 + l16;
    f32x4 acc[8] = {};
    #pragma unroll
    for (int kk = 0; kk < 4; ++kk) {
        half8 af;
        if (Arow < n) {
            const float* ap = x + (size_t)Arow * H + kk * 32 + quad * 8;
            float4 a0 = ((const float4*)ap)[0];
            float4 a1 = ((const float4*)ap)[1];
            af[0] = (_Float16)a0.x; af[1] = (_Float16)a0.y;
            af[2] = (_Float16)a0.z; af[3] = (_Float16)a0.w;
            af[4] = (_Float16)a1.x; af[5] = (_Float16)a1.y;
            af[6] = (_Float16)a1.z; af[7] = (_Float16)a1.w;
        } else {
            #pragma unroll
            for (int j = 0; j < 8; ++j) af[j] = (_Float16)0.0f;
        }
        #pragma unroll
        for (int nt = 0; nt < 8; ++nt) {
            half8 bf = *((const half8*)(Wt1 + (nt * 16 + l16) * H + kk * 32 + quad * 8));
            acc[nt] = __builtin_amdgcn_mfma_f32_16x16x32_f16(af, bf, acc[nt], 0, 0, 0);
        }
    }
    #pragma unroll
    for (int r = 0; r < 4; ++r) {
        int R = row0 + w * 16 + quad * 4 + r;
        if (R < n) {
            float sc = dinv[R];
            _Float16* crow = tS + (size_t)R * H + l16;
            #pragma unroll
            for (int nt = 0; nt < 8; ++nt)
                crow[nt * 16] = (_Float16)(acc[nt][r] * sc);
        }
    }
}

// ---------------------------------------------------------------------------
// GEMM2, LDS-free: tS2 = (h1 @ W2) * dinv[row]
__global__ __launch_bounds__(256) void k_gemm2(const _Float16* __restrict__ h1,
                                               const _Float16* __restrict__ Wt2,
                                               const float* __restrict__ dinv,
                                               _Float16* __restrict__ tS2, int n) {
    const int row0 = blockIdx.x * 64;
    const int tid = threadIdx.x;
    const int w = tid >> 6, lane = tid & 63;
    const int l16 = lane & 15, quad = lane >> 4;
    const int Arow = row0 + w * 16 + l16;
    f32x4 acc[8] = {};
    #pragma unroll
    for (int kk = 0; kk < 4; ++kk) {
        half8 af;
        if (Arow < n) {
            af = ((const half8*)(h1 + (size_t)Arow * H))[kk * 4 + quad];
        } else {
            #pragma unroll
            for (int j = 0; j < 8; ++j) af[j] = (_Float16)0.0f;
        }
        #pragma unroll
        for (int nt = 0; nt < 8; ++nt) {
            half8 bf = *((const half8*)(Wt2 + (nt * 16 + l16) * H + kk * 32 + quad * 8));
            acc[nt] = __builtin_amdgcn_mfma_f32_16x16x32_f16(af, bf, acc[nt], 0, 0, 0);
        }
    }
    #pragma unroll
    for (int r = 0; r < 4; ++r) {
        int R = row0 + w * 16 + quad * 4 + r;
        if (R < n) {
            float sc = dinv[R];
            _Float16* crow = tS2 + (size_t)R * H + l16;
            #pragma unroll
            for (int nt = 0; nt < 8; ++nt)
                crow[nt * 16] = (_Float16)(acc[nt][r] * sc);
        }
    }
}

// ---------------------------------------------------------------------------
// INLINE-ASM 8-deep burst gather core.
// r5 post-mortem: every source-level burst formulation (r1 masked, r4 dual-
// chain, r5 uniform ladder) was re-serialized by hipcc to 2-in-flight
// (VGPR_Count pinned at 28-36 every round). This block is the compiler-proof
// form: ONE asm volatile containing all 8 global_load_dwordx4 AND the
// s_waitcnt vmcnt(0). Outputs are dataflow-dependent on the block and the
// wait is inside it -> no hoist hazard, no re-serialization possible.
// Always issues 8 groups (32 edges, covers >=99.99% of Poisson(16) nodes);
// invalid groups load the node's own row (L1-warm broadcast) with weight 0.
// Rare deg>32 tail handled by a chunked loop afterwards.
__device__ __forceinline__ void gather_burst(const _Float16* __restrict__ tS,
                                             const int* __restrict__ col,
                                             int node, int e0, int e1,
                                             float acc[8]) {
    const int lane = threadIdx.x & 63;
    const int q = lane >> 4;
    const int l16 = lane & 15;
    const int m = e1 - e0;
    int cidx = (e0 + lane < e1) ? col[e0 + lane] : node;   // clamp -> safe row
    float a0[8] = {}, a1[8] = {};

    // self-loop row: all lanes load (broadcast lines), quarter 0 accumulates
    {
        half8 v = ((const half8*)tS)[(size_t)node * 16 + l16];
        float w = (q == 0) ? 1.0f : 0.0f;
        #pragma unroll
        for (int i = 0; i < 8; ++i) a0[i] = w * (float)v[i];
    }

    const char* base = (const char*)tS;
    const uint32_t fo = (uint32_t)(l16 << 4);
#define ROWP(G) (const void*)(base + ((((uint32_t)__shfl(cidx, 4 * (G) + q)) << 8) + fo))
    const void* p0 = ROWP(0);
    const void* p1 = ROWP(1);
    const void* p2 = ROWP(2);
    const void* p3 = ROWP(3);
    const void* p4 = ROWP(4);
    const void* p5 = ROWP(5);
    const void* p6 = ROWP(6);
    const void* p7 = ROWP(7);
#undef ROWP

    f32x4 r0, r1, r2, r3, r4, r5, r6, r7;
    asm volatile(
        "global_load_dwordx4 %0, %8, off\n\t"
        "global_load_dwordx4 %1, %9, off\n\t"
        "global_load_dwordx4 %2, %10, off\n\t"
        "global_load_dwordx4 %3, %11, off\n\t"
        "global_load_dwordx4 %4, %12, off\n\t"
        "global_load_dwordx4 %5, %13, off\n\t"
        "global_load_dwordx4 %6, %14, off\n\t"
        "global_load_dwordx4 %7, %15, off\n\t"
        "s_waitcnt vmcnt(0)"
        : "=&v"(r0), "=&v"(r1), "=&v"(r2), "=&v"(r3),
          "=&v"(r4), "=&v"(r5), "=&v"(r6), "=&v"(r7)
        : "v"(p0), "v"(p1), "v"(p2), "v"(p3),
          "v"(p4), "v"(p5), "v"(p6), "v"(p7)
        : "memory");

    // accumulate (per-lane validity weight; only the last group is partial)
#define G_ACC(G, R, A) { h8f4 u_; u_.f = (R); \
        float w_ = (4 * (G) + q < m) ? 1.0f : 0.0f; \
        _Pragma("unroll") \
        for (int i = 0; i < 8; ++i) (A)[i] += w_ * (float)u_.h[i]; }
    G_ACC(0, r0, a0)
    G_ACC(1, r1, a1)
    G_ACC(2, r2, a0)
    G_ACC(3, r3, a1)
    G_ACC(4, r4, a0)
    G_ACC(5, r5, a1)
    G_ACC(6, r6, a0)
    G_ACC(7, r7, a1)
#undef G_ACC

    // ---- rare tail: deg > 32 (P ~ 1e-4) ----
    for (int base2 = e0 + 32; base2 < e1; base2 += 64) {
        int ce = base2 + lane;
        int cx = (ce < e1) ? col[ce] : node;
        int mm = min(64, e1 - base2);
        int nf2 = (mm + 3) >> 2;
        for (int g = 0; g < nf2; ++g) {
            int s_ = __shfl(cx, 4 * g + q);
            half8 v = ((const half8*)tS)[(size_t)s_ * 16 + l16];
            float w_ = (4 * g + q < mm) ? 1.0f : 0.0f;
            #pragma unroll
            for (int i = 0; i < 8; ++i) a0[i] += w_ * (float)v[i];
        }
    }

    #pragma unroll
    for (int i = 0; i < 8; ++i) {
        float t = a0[i] + a1[i];
        t += __shfl_xor(t, 16);
        t += __shfl_xor(t, 32);
        acc[i] = t;
    }
}

// gather layer 1: out (fp16) = relu(dinv[n]*(tS[n] + sum in-edges) + b)
__global__ __launch_bounds__(256, 4) void k_gather1(const _Float16* __restrict__ tS,
                                                    const int* __restrict__ rowptr,
                                                    const int* __restrict__ col,
                                                    const float* __restrict__ dinv,
                                                    const float* __restrict__ b,
                                                    _Float16* __restrict__ out, int n) {
    int node = blockIdx.x * 4 + (threadIdx.x >> 6);
    int lane = threadIdx.x & 63;
    int q = lane >> 4, l16 = lane & 15;
    if (node >= n) return;
    int e0 = rowptr[node], e1 = rowptr[node + 1];
    float acc[8];
    gather_burst(tS, col, node, e0, e1, acc);
    if (q == 0) {
        float dn = dinv[node];
        const float4* b4 = (const float4*)b;
        float4 bb0 = b4[2 * l16], bb1 = b4[2 * l16 + 1];
        half8 hv;
        hv[0] = (_Float16)fmaxf(dn * acc[0] + bb0.x, 0.0f);
        hv[1] = (_Float16)fmaxf(dn * acc[1] + bb0.y, 0.0f);
        hv[2] = (_Float16)fmaxf(dn * acc[2] + bb0.z, 0.0f);
        hv[3] = (_Float16)fmaxf(dn * acc[3] + bb0.w, 0.0f);
        hv[4] = (_Float16)fmaxf(dn * acc[4] + bb1.x, 0.0f);
        hv[5] = (_Float16)fmaxf(dn * acc[5] + bb1.y, 0.0f);
        hv[6] = (_Float16)fmaxf(dn * acc[6] + bb1.z, 0.0f);
        hv[7] = (_Float16)fmaxf(dn * acc[7] + bb1.w, 0.0f);
        ((half8*)out)[(size_t)node * 16 + l16] = hv;
    }
}

// gather layer 2 fused with pool head: v = relu(...); pool[batch[n]] += dot(v, Wp)
__global__ __launch_bounds__(256, 4) void k_gather2(const _Float16* __restrict__ tS,
                                                    const int* __restrict__ rowptr,
                                                    const int* __restrict__ col,
                                                    const float* __restrict__ dinv,
                                                    const float* __restrict__ b,
                                                    const float* __restrict__ Wp,
                                                    const int* __restrict__ batch,
                                                    float* __restrict__ pool, int n) {
    int node = blockIdx.x * 4 + (threadIdx.x >> 6);
    int lane = threadIdx.x & 63;
    int l16 = lane & 15;
    if (node >= n) return;
    int e0 = rowptr[node], e1 = rowptr[node + 1];
    float acc[8];
    gather_burst(tS, col, node, e0, e1, acc);
    float dn = dinv[node];
    const float4* b4 = (const float4*)b;
    const float4* w4 = (const float4*)Wp;
    float4 bb0 = b4[2 * l16], bb1 = b4[2 * l16 + 1];
    float4 wp0 = w4[2 * l16], wp1 = w4[2 * l16 + 1];
    float s = fmaxf(dn * acc[0] + bb0.x, 0.0f) * wp0.x +
              fmaxf(dn * acc[1] + bb0.y, 0.0f) * wp0.y +
              fmaxf(dn * acc[2] + bb0.z, 0.0f) * wp0.z +
              fmaxf(dn * acc[3] + bb0.w, 0.0f) * wp0.w +
              fmaxf(dn * acc[4] + bb1.x, 0.0f) * wp1.x +
              fmaxf(dn * acc[5] + bb1.y, 0.0f) * wp1.y +
              fmaxf(dn * acc[6] + bb1.z, 0.0f) * wp1.z +
              fmaxf(dn * acc[7] + bb1.w, 0.0f) * wp1.w;
    s += __shfl_xor(s, 1);
    s += __shfl_xor(s, 2);
    s += __shfl_xor(s, 4);
    s += __shfl_xor(s, 8);
    if (lane == 0) {
        int g = batch[node];
        atomicAdd(&pool[g], s);
    }
}

// ---------------------------------------------------------------------------
// batch is sorted: per-graph node counts via binary search (replaces 100K
// float atomics previously done in gather2).
__global__ __launch_bounds__(256) void final_out_kernel(const float* __restrict__ pool,
                                                        const int* __restrict__ batch,
                                                        const float* __restrict__ bp,
                                                        float* __restrict__ out, int g) {
    int i = blockIdx.x * 256 + threadIdx.x;
    if (i >= g) return;
    int lo = 0, hi = NN;
    while (lo < hi) { int mid = (lo + hi) >> 1; if (batch[mid] < i) lo = mid + 1; else hi = mid; }
    int s0 = lo;
    hi = NN;
    while (lo < hi) { int mid = (lo + hi) >> 1; if (batch[mid] < i + 1) lo = mid + 1; else hi = mid; }
    float c = (float)(lo - s0);
    out[i] = pool[i] / fmaxf(c, 1.0f) + bp[0];
}

// ---------------------------------------------------------------------------
extern "C" void kernel_launch(void* const* d_in, const int* in_sizes, int n_in,
                              void* d_out, int out_size, void* d_ws, size_t ws_size,
                              hipStream_t stream) {
    const float* x     = (const float*)d_in[0];
    const int*   ei    = (const int*)d_in[1];   // [2, E]: src = ei[0:E], dst = ei[E:2E]
    const int*   batch = (const int*)d_in[2];
    const float* W1    = (const float*)d_in[3];
    const float* b1    = (const float*)d_in[4];
    const float* W2    = (const float*)d_in[5];
    const float* b2    = (const float*)d_in[6];
    const float* Wp    = (const float*)d_in[7];
    const float* bp    = (const float*)d_in[8];
    float* out = (float*)d_out;

    const int E = in_sizes[1] / 2;   // 1,600,000
    const int* src = ei;
    const int* dst = ei + E;

    // workspace layout
    const size_t BUFH = (size_t)NN * H * sizeof(_Float16);   // 25.6 MB
    const size_t NI   = 401408;                               // >= (NN+1)*4, 4KB-mult
    char* ws = (char*)d_ws;
    size_t off = 0;
    _Float16* tS   = (_Float16*)(ws + off); off += BUFH;     // GEMM1 out (fp16)
    _Float16* h1   = (_Float16*)(ws + off); off += BUFH;     // layer-1 acts (fp16)
    _Float16* tS2  = (_Float16*)(ws + off); off += BUFH;     // GEMM2 out (fp16)
    int*      deg  = (int*)     (ws + off); off += NI;
    int*   rowptr  = (int*)     (ws + off); off += NI;
    int*   cursor  = (int*)     (ws + off); off += NI;
    float*    dinv = (float*)   (ws + off); off += NI;
    int*      col  = (int*)     (ws + off); off += ((size_t)E * 4 + 4095) / 4096 * 4096;
    _Float16* Wt1  = (_Float16*)(ws + off); off += 32768;
    _Float16* Wt2  = (_Float16*)(ws + off); off += 32768;
    int*      bsum = (int*)     (ws + off); off += 4096;
    float*    pool = (float*)   (ws + off); off += 2048;

    const int NB  = (NN + 255) / 256;   // 391 scan blocks
    const int NFB = (E + 255) / 256;    // 6250 fill/hist blocks
    const int NGB = (NN + 63) / 64;     // 1563 gemm blocks
    const int NGA = (NN + 3) / 4;       // 25000 gather blocks (4 nodes/block)

    // --- weights prep ∥ histogram (one dispatch), then scans ---
    hipMemsetAsync(deg, 0, NN * sizeof(int), stream);
    hipMemsetAsync(pool, 0, 2048, stream);
    k_wprep_hist<<<128 + NFB, 256, 0, stream>>>(W1, W2, Wt1, Wt2, dst, deg, E);
    k_scan_block<<<NB, 256, 0, stream>>>(deg, rowptr, bsum, NN);
    k_scan_top<<<1, 512, 0, stream>>>(bsum, NB);
    k_scan_fin<<<NB, 256, 0, stream>>>(rowptr, bsum, deg, cursor, dinv, NN, E);

    // --- fill CSR  ∥  GEMM1 (one dispatch, disjoint block ranges) ---
    k_fill_gemm1<<<NFB + NGB, 256, 0, stream>>>(src, dst, cursor, col, E, NFB,
                                                x, Wt1, dinv, tS, NN);

    // --- layer 1: asm-burst gather then LDS-free MFMA GEMM2 ---
    k_gather1<<<NGA, 256, 0, stream>>>(tS, rowptr, col, dinv, b1, h1, NN);
    k_gemm2<<<NGB, 256, 0, stream>>>(h1, Wt2, dinv, tS2, NN);

    // --- layer 2 asm-burst gather + pool head ---
    k_gather2<<<NGA, 256, 0, stream>>>(tS2, rowptr, col, dinv, b2, Wp,
                                       batch, pool, NN);

    // --- head ---
    final_out_kernel<<<(NG + 255) / 256, 256, 0, stream>>>(pool, batch, bp, out, NG);
}

// Round 7
// 673.498 us; speedup vs baseline: 1.0883x; 1.0391x over previous
//
#include <hip/hip_runtime.h>
#include <hip/hip_bf16.h>

// Problem constants (match reference)
#define NN 100000
#define NG 512
#define H  128

typedef _Float16 half8 __attribute__((ext_vector_type(8)));
typedef float f32x4 __attribute__((ext_vector_type(4)));

// ---------------------------------------------------------------------------
// Merged: blocks [0,128) transpose+fp16-convert W1/W2; blocks [128,..) dst hist
__global__ __launch_bounds__(256) void k_wprep_hist(const float* __restrict__ W1,
                                                    const float* __restrict__ W2,
                                                    _Float16* __restrict__ Wt1,
                                                    _Float16* __restrict__ Wt2,
                                                    const int* __restrict__ dst,
                                                    int* __restrict__ deg, int E) {
    int bb = blockIdx.x;
    if (bb < 128) {
        const float* W = (bb < 64) ? W1 : W2;
        _Float16* Wt = (bb < 64) ? Wt1 : Wt2;
        int i = (bb & 63) * 256 + threadIdx.x;    // 0..16383
        int k = i >> 7, n = i & 127;
        Wt[n * 128 + k] = (_Float16)W[i];
        return;
    }
    int e = (bb - 128) * 256 + threadIdx.x;
    if (e < E) atomicAdd(&deg[dst[e]], 1);
}

// per-block exclusive scan (256 elems), partial sums to bsum
__global__ __launch_bounds__(256) void k_scan_block(const int* __restrict__ deg,
                                                    int* __restrict__ rowptr,
                                                    int* __restrict__ bsum, int n) {
    __shared__ int s[256];
    int tid = threadIdx.x;
    int i = blockIdx.x * 256 + tid;
    int v = (i < n) ? deg[i] : 0;
    s[tid] = v;
    __syncthreads();
    #pragma unroll
    for (int off = 1; off < 256; off <<= 1) {
        int t = (tid >= off) ? s[tid - off] : 0;
        __syncthreads();
        s[tid] += t;
        __syncthreads();
    }
    if (i < n) rowptr[i] = s[tid] - v;            // exclusive within block
    if (tid == 255) bsum[blockIdx.x] = s[255];    // block total
}

// scan of block sums (nb <= 512), single block
__global__ __launch_bounds__(512) void k_scan_top(int* __restrict__ bsum, int nb) {
    __shared__ int s[512];
    int tid = threadIdx.x;
    int v = (tid < nb) ? bsum[tid] : 0;
    s[tid] = v;
    __syncthreads();
    #pragma unroll
    for (int off = 1; off < 512; off <<= 1) {
        int t = (tid >= off) ? s[tid - off] : 0;
        __syncthreads();
        s[tid] += t;
        __syncthreads();
    }
    if (tid < nb) bsum[tid] = s[tid] - v;         // exclusive
}

// finalize: rowptr += block offset; cursor = rowptr; dinv = rsqrt(deg+1)
__global__ __launch_bounds__(256) void k_scan_fin(int* __restrict__ rowptr,
                                                  const int* __restrict__ bsum,
                                                  const int* __restrict__ deg,
                                                  int* __restrict__ cursor,
                                                  float* __restrict__ dinv,
                                                  int n, int E) {
    int i = blockIdx.x * 256 + threadIdx.x;
    if (i >= n) return;
    int r = rowptr[i] + bsum[i >> 8];
    rowptr[i] = r;
    cursor[i] = r;
    dinv[i] = rsqrtf((float)deg[i] + 1.0f);       // +1 self-loop; always > 0
    if (i == 0) rowptr[n] = E;
}

// ---------------------------------------------------------------------------
// Fused: blocks [0,nfb) fill CSR col; blocks [nfb,..) do GEMM1
// (tS = (x@W1)*dinv[row], fp16 out). LDS-free MFMA GEMM.
__global__ __launch_bounds__(256) void k_fill_gemm1(
        const int* __restrict__ src, const int* __restrict__ dst,
        int* __restrict__ cursor, int* __restrict__ col, int E, int nfb,
        const float* __restrict__ x, const _Float16* __restrict__ Wt1,
        const float* __restrict__ dinv, _Float16* __restrict__ tS, int n) {
    if ((int)blockIdx.x < nfb) {
        int e = blockIdx.x * 256 + threadIdx.x;
        if (e >= E) return;
        int d = dst[e];
        int pos = atomicAdd(&cursor[d], 1);
        col[pos] = src[e];
        return;
    }
    const int row0 = ((int)blockIdx.x - nfb) * 64;
    const int tid = threadIdx.x;
    const int w = tid >> 6, lane = tid & 63;
    const int l16 = lane & 15, quad = lane >> 4;
    const int Arow = row0 + w * 16 + l16;
    f32x4 acc[8] = {};
    #pragma unroll
    for (int kk = 0; kk < 4; ++kk) {
        half8 af;
        if (Arow < n) {
            const float* ap = x + (size_t)Arow * H + kk * 32 + quad * 8;
            float4 a0 = ((const float4*)ap)[0];
            float4 a1 = ((const float4*)ap)[1];
            af[0] = (_Float16)a0.x; af[1] = (_Float16)a0.y;
            af[2] = (_Float16)a0.z; af[3] = (_Float16)a0.w;
            af[4] = (_Float16)a1.x; af[5] = (_Float16)a1.y;
            af[6] = (_Float16)a1.z; af[7] = (_Float16)a1.w;
        } else {
            #pragma unroll
            for (int j = 0; j < 8; ++j) af[j] = (_Float16)0.0f;
        }
        #pragma unroll
        for (int nt = 0; nt < 8; ++nt) {
            half8 bf = *((const half8*)(Wt1 + (nt * 16 + l16) * H + kk * 32 + quad * 8));
            acc[nt] = __builtin_amdgcn_mfma_f32_16x16x32_f16(af, bf, acc[nt], 0, 0, 0);
        }
    }
    #pragma unroll
    for (int r = 0; r < 4; ++r) {
        int R = row0 + w * 16 + quad * 4 + r;
        if (R < n) {
            float sc = dinv[R];
            _Float16* crow = tS + (size_t)R * H + l16;
            #pragma unroll
            for (int nt = 0; nt < 8; ++nt)
                crow[nt * 16] = (_Float16)(acc[nt][r] * sc);
        }
    }
}

// ---------------------------------------------------------------------------
// GEMM2, LDS-free: tS2 = (h1 @ W2) * dinv[row]
__global__ __launch_bounds__(256) void k_gemm2(const _Float16* __restrict__ h1,
                                               const _Float16* __restrict__ Wt2,
                                               const float* __restrict__ dinv,
                                               _Float16* __restrict__ tS2, int n) {
    const int row0 = blockIdx.x * 64;
    const int tid = threadIdx.x;
    const int w = tid >> 6, lane = tid & 63;
    const int l16 = lane & 15, quad = lane >> 4;
    const int Arow = row0 + w * 16 + l16;
    f32x4 acc[8] = {};
    #pragma unroll
    for (int kk = 0; kk < 4; ++kk) {
        half8 af;
        if (Arow < n) {
            af = ((const half8*)(h1 + (size_t)Arow * H))[kk * 4 + quad];
        } else {
            #pragma unroll
            for (int j = 0; j < 8; ++j) af[j] = (_Float16)0.0f;
        }
        #pragma unroll
        for (int nt = 0; nt < 8; ++nt) {
            half8 bf = *((const half8*)(Wt2 + (nt * 16 + l16) * H + kk * 32 + quad * 8));
            acc[nt] = __builtin_amdgcn_mfma_f32_16x16x32_f16(af, bf, acc[nt], 0, 0, 0);
        }
    }
    #pragma unroll
    for (int r = 0; r < 4; ++r) {
        int R = row0 + w * 16 + quad * 4 + r;
        if (R < n) {
            float sc = dinv[R];
            _Float16* crow = tS2 + (size_t)R * H + l16;
            #pragma unroll
            for (int nt = 0; nt < 8; ++nt)
                crow[nt * 16] = (_Float16)(acc[nt][r] * sc);
        }
    }
}

// ---------------------------------------------------------------------------
// 16B row-fragment load that BYPASSES L1 (agent-scope relaxed atomic ->
// global_load_dwordx2 sc0). Used ONLY in gather2 (no store stream there;
// measured −4% in gather2, regression in store-heavy gather1).
__device__ __forceinline__ half8 ld_row16_nol1(const _Float16* p) {
    union { unsigned long long u[2]; half8 h; } t;
    const unsigned long long* q = (const unsigned long long*)p;
    t.u[0] = __hip_atomic_load(q,     __ATOMIC_RELAXED, __HIP_MEMORY_SCOPE_AGENT);
    t.u[1] = __hip_atomic_load(q + 1, __ATOMIC_RELAXED, __HIP_MEMORY_SCOPE_AGENT);
    return t.h;
}

// Gather core, fp16 rows (256B). One wave per node; quarter-wave q handles
// edge slot 4g+q; lane loads 16B (8 halves) of the row. col indices
// bulk-loaded 64 at a time, broadcast by shfl. fp32 accumulate; after
// xor-16/32 all lanes hold the full sum for feats l16*8..+7.
// NOTE (session r0-r6): this exact 2-in-flight form is the best-measured
// core. Deeper bursts (4/8-deep, incl. hardware-verified inline-asm 8-deep),
// pair-preludes, feature-sliced passes, and occupancy changes are ALL null:
// the gather sits at a ~6.8 G scattered-row-requests/s service wall with
// L2 hit rate already at its structural cap (per-XCD reuse = E/(8N) = 2).
// Do not re-attempt per-wave MLP here.
template <bool NOL1>
__device__ __forceinline__ void gather_rows_h(const _Float16* __restrict__ tS,
                                              const int* __restrict__ col,
                                              int node, int e0, int end,
                                              float acc[8]) {
    const int lane = threadIdx.x & 63;
    const int q = lane >> 4;
    const int l16 = lane & 15;
    float a0[8] = {}, a1[8] = {};
    if (q == 0) {                                   // self-loop row (cached load)
        half8 v = ((const half8*)tS)[(size_t)node * 16 + l16];
        #pragma unroll
        for (int i = 0; i < 8; ++i) a0[i] = (float)v[i];
    }
    for (int base = e0; base < end; base += 64) {
        int ce = base + lane;
        int cidx = (ce < end) ? col[ce] : 0;
        int m = min(64, end - base);
        int nf = m >> 2;                            // full groups of 4 edges
        int g = 0;
        for (; g + 2 <= nf; g += 2) {
            int s0 = __shfl(cidx, 4 * g + q);
            int s1 = __shfl(cidx, 4 * g + 4 + q);
            half8 v0, v1;
            if (NOL1) {
                v0 = ld_row16_nol1(tS + (size_t)s0 * H + l16 * 8);
                v1 = ld_row16_nol1(tS + (size_t)s1 * H + l16 * 8);
            } else {
                v0 = ((const half8*)tS)[(size_t)s0 * 16 + l16];
                v1 = ((const half8*)tS)[(size_t)s1 * 16 + l16];
            }
            #pragma unroll
            for (int i = 0; i < 8; ++i) {
                a0[i] += (float)v0[i];
                a1[i] += (float)v1[i];
            }
        }
        if (g < nf) {
            int s0 = __shfl(cidx, 4 * g + q);
            half8 v0 = NOL1 ? ld_row16_nol1(tS + (size_t)s0 * H + l16 * 8)
                            : ((const half8*)tS)[(size_t)s0 * 16 + l16];
            #pragma unroll
            for (int i = 0; i < 8; ++i) a0[i] += (float)v0[i];
        }
        int tail = m & 3;
        if (tail) {
            int s = __shfl(cidx, 4 * nf + q);       // all lanes active here
            if (q < tail) {
                half8 v = NOL1 ? ld_row16_nol1(tS + (size_t)s * H + l16 * 8)
                               : ((const half8*)tS)[(size_t)s * 16 + l16];
                #pragma unroll
                for (int i = 0; i < 8; ++i) a0[i] += (float)v[i];
            }
        }
    }
    #pragma unroll
    for (int i = 0; i < 8; ++i) {
        float t = a0[i] + a1[i];
        t += __shfl_xor(t, 16);
        t += __shfl_xor(t, 32);
        acc[i] = t;
    }
}

// gather layer 1: out (fp16) = relu(dinv[n]*(tS[n] + sum in-edges) + b)
__global__ __launch_bounds__(256) void k_gather1(const _Float16* __restrict__ tS,
                                                 const int* __restrict__ rowptr,
                                                 const int* __restrict__ col,
                                                 const float* __restrict__ dinv,
                                                 const float* __restrict__ b,
                                                 _Float16* __restrict__ out, int n) {
    int node = blockIdx.x * 4 + (threadIdx.x >> 6);
    int lane = threadIdx.x & 63;
    int q = lane >> 4, l16 = lane & 15;
    if (node >= n) return;
    int e0 = rowptr[node], end = rowptr[node + 1];
    float acc[8];
    gather_rows_h<false>(tS, col, node, e0, end, acc);
    if (q == 0) {
        float dn = dinv[node];
        const float4* b4 = (const float4*)b;
        float4 bb0 = b4[2 * l16], bb1 = b4[2 * l16 + 1];
        half8 hv;
        hv[0] = (_Float16)fmaxf(dn * acc[0] + bb0.x, 0.0f);
        hv[1] = (_Float16)fmaxf(dn * acc[1] + bb0.y, 0.0f);
        hv[2] = (_Float16)fmaxf(dn * acc[2] + bb0.z, 0.0f);
        hv[3] = (_Float16)fmaxf(dn * acc[3] + bb0.w, 0.0f);
        hv[4] = (_Float16)fmaxf(dn * acc[4] + bb1.x, 0.0f);
        hv[5] = (_Float16)fmaxf(dn * acc[5] + bb1.y, 0.0f);
        hv[6] = (_Float16)fmaxf(dn * acc[6] + bb1.z, 0.0f);
        hv[7] = (_Float16)fmaxf(dn * acc[7] + bb1.w, 0.0f);
        ((half8*)out)[(size_t)node * 16 + l16] = hv;
    }
}

// gather layer 2 fused with pool head: v = relu(...); pool[batch[n]] += dot(v, Wp)
// (cnt atomics removed — counts recovered by binary search in final kernel)
__global__ __launch_bounds__(256) void k_gather2(const _Float16* __restrict__ tS,
                                                 const int* __restrict__ rowptr,
                                                 const int* __restrict__ col,
                                                 const float* __restrict__ dinv,
                                                 const float* __restrict__ b,
                                                 const float* __restrict__ Wp,
                                                 const int* __restrict__ batch,
                                                 float* __restrict__ pool, int n) {
    int node = blockIdx.x * 4 + (threadIdx.x >> 6);
    int lane = threadIdx.x & 63;
    int l16 = lane & 15;
    if (node >= n) return;
    int e0 = rowptr[node], end = rowptr[node + 1];
    float acc[8];
    gather_rows_h<true>(tS, col, node, e0, end, acc);
    float dn = dinv[node];
    const float4* b4 = (const float4*)b;
    const float4* w4 = (const float4*)Wp;
    float4 bb0 = b4[2 * l16], bb1 = b4[2 * l16 + 1];
    float4 wp0 = w4[2 * l16], wp1 = w4[2 * l16 + 1];
    float s = fmaxf(dn * acc[0] + bb0.x, 0.0f) * wp0.x +
              fmaxf(dn * acc[1] + bb0.y, 0.0f) * wp0.y +
              fmaxf(dn * acc[2] + bb0.z, 0.0f) * wp0.z +
              fmaxf(dn * acc[3] + bb0.w, 0.0f) * wp0.w +
              fmaxf(dn * acc[4] + bb1.x, 0.0f) * wp1.x +
              fmaxf(dn * acc[5] + bb1.y, 0.0f) * wp1.y +
              fmaxf(dn * acc[6] + bb1.z, 0.0f) * wp1.z +
              fmaxf(dn * acc[7] + bb1.w, 0.0f) * wp1.w;
    s += __shfl_xor(s, 1);
    s += __shfl_xor(s, 2);
    s += __shfl_xor(s, 4);
    s += __shfl_xor(s, 8);
    if (lane == 0) {
        int g = batch[node];
        atomicAdd(&pool[g], s);
    }
}

// ---------------------------------------------------------------------------
// batch is sorted: per-graph node counts via binary search (replaces 100K
// float atomics previously done in gather2).
__global__ __launch_bounds__(256) void final_out_kernel(const float* __restrict__ pool,
                                                        const int* __restrict__ batch,
                                                        const float* __restrict__ bp,
                                                        float* __restrict__ out, int g) {
    int i = blockIdx.x * 256 + threadIdx.x;
    if (i >= g) return;
    int lo = 0, hi = NN;
    while (lo < hi) { int mid = (lo + hi) >> 1; if (batch[mid] < i) lo = mid + 1; else hi = mid; }
    int s0 = lo;
    hi = NN;
    while (lo < hi) { int mid = (lo + hi) >> 1; if (batch[mid] < i + 1) lo = mid + 1; else hi = mid; }
    float c = (float)(lo - s0);
    out[i] = pool[i] / fmaxf(c, 1.0f) + bp[0];
}

// ---------------------------------------------------------------------------
extern "C" void kernel_launch(void* const* d_in, const int* in_sizes, int n_in,
                              void* d_out, int out_size, void* d_ws, size_t ws_size,
                              hipStream_t stream) {
    const float* x     = (const float*)d_in[0];
    const int*   ei    = (const int*)d_in[1];   // [2, E]: src = ei[0:E], dst = ei[E:2E]
    const int*   batch = (const int*)d_in[2];
    const float* W1    = (const float*)d_in[3];
    const float* b1    = (const float*)d_in[4];
    const float* W2    = (const float*)d_in[5];
    const float* b2    = (const float*)d_in[6];
    const float* Wp    = (const float*)d_in[7];
    const float* bp    = (const float*)d_in[8];
    float* out = (float*)d_out;

    const int E = in_sizes[1] / 2;   // 1,600,000
    const int* src = ei;
    const int* dst = ei + E;

    // workspace layout
    const size_t BUFH = (size_t)NN * H * sizeof(_Float16);   // 25.6 MB
    const size_t NI   = 401408;                               // >= (NN+1)*4, 4KB-mult
    char* ws = (char*)d_ws;
    size_t off = 0;
    _Float16* tS   = (_Float16*)(ws + off); off += BUFH;     // GEMM1 out (fp16)
    _Float16* h1   = (_Float16*)(ws + off); off += BUFH;     // layer-1 acts (fp16)
    _Float16* tS2  = (_Float16*)(ws + off); off += BUFH;     // GEMM2 out (fp16)
    int*      deg  = (int*)     (ws + off); off += NI;
    int*   rowptr  = (int*)     (ws + off); off += NI;
    int*   cursor  = (int*)     (ws + off); off += NI;
    float*    dinv = (float*)   (ws + off); off += NI;
    int*      col  = (int*)     (ws + off); off += ((size_t)E * 4 + 4095) / 4096 * 4096;
    _Float16* Wt1  = (_Float16*)(ws + off); off += 32768;
    _Float16* Wt2  = (_Float16*)(ws + off); off += 32768;
    int*      bsum = (int*)     (ws + off); off += 4096;
    float*    pool = (float*)   (ws + off); off += 2048;

    const int NB  = (NN + 255) / 256;   // 391 scan blocks
    const int NFB = (E + 255) / 256;    // 6250 fill/hist blocks
    const int NGB = (NN + 63) / 64;     // 1563 gemm blocks
    const int NGA = (NN + 3) / 4;       // 25000 gather blocks (4 nodes/block)

    // --- weights prep ∥ histogram (one dispatch), then scans ---
    hipMemsetAsync(deg, 0, NN * sizeof(int), stream);
    hipMemsetAsync(pool, 0, 2048, stream);
    k_wprep_hist<<<128 + NFB, 256, 0, stream>>>(W1, W2, Wt1, Wt2, dst, deg, E);
    k_scan_block<<<NB, 256, 0, stream>>>(deg, rowptr, bsum, NN);
    k_scan_top<<<1, 512, 0, stream>>>(bsum, NB);
    k_scan_fin<<<NB, 256, 0, stream>>>(rowptr, bsum, deg, cursor, dinv, NN, E);

    // --- fill CSR  ∥  GEMM1 (one dispatch, disjoint block ranges) ---
    k_fill_gemm1<<<NFB + NGB, 256, 0, stream>>>(src, dst, cursor, col, E, NFB,
                                                x, Wt1, dinv, tS, NN);

    // --- layer 1: gather (wave/node) then LDS-free MFMA GEMM2 ---
    k_gather1<<<NGA, 256, 0, stream>>>(tS, rowptr, col, dinv, b1, h1, NN);
    k_gemm2<<<NGB, 256, 0, stream>>>(h1, Wt2, dinv, tS2, NN);

    // --- layer 2 gather + pool head ---
    k_gather2<<<NGA, 256, 0, stream>>>(tS2, rowptr, col, dinv, b2, Wp,
                                       batch, pool, NN);

    // --- head ---
    final_out_kernel<<<(NG + 255) / 256, 256, 0, stream>>>(pool, batch, bp, out, NG);
}